// Round 4
// baseline (438.893 us; speedup 1.0000x reference)
//
#include <hip/hip_runtime.h>
#include <hip/hip_bf16.h>

#define NB 32
#define NN 784
#define NNP 896        // N padded to 7*128 k-chunks
#define DIMC 512
#define NH 8
#define KD 32
#define VD 128
#define QKV_OUT 1536
#define VAL_ATTN 1024
#define PROW 136       // P LDS row stride (ushorts)
#define KROW 40        // K LDS row stride (ushorts)

typedef __attribute__((ext_vector_type(4))) float floatx4;
typedef __attribute__((ext_vector_type(8))) short shortx8;
typedef __attribute__((ext_vector_type(4))) unsigned short ushortx4;
typedef __attribute__((ext_vector_type(4))) unsigned int uintx4;
typedef unsigned short ushort_t;

__device__ __forceinline__ unsigned short f2bf(float f) {
    union { float f; unsigned int u; } v; v.f = f;
    unsigned int r = v.u + 0x7fffu + ((v.u >> 16) & 1u);
    return (unsigned short)(r >> 16);
}
__device__ __forceinline__ float bf2f(unsigned short s) {
    union { unsigned int u; float f; } v; v.u = ((unsigned int)s) << 16;
    return v.f;
}
__device__ __forceinline__ void gld16(void* lds, const void* g) {
    __builtin_amdgcn_global_load_lds((const __attribute__((address_space(1))) void*)g,
                                     (__attribute__((address_space(3))) void*)lds, 16, 0, 0);
}

// ---------------- fp32 -> bf16 bulk convert ----------------
__global__ void cvt_bf16(const float* __restrict__ in, ushort_t* __restrict__ out, int n4) {
    int i = blockIdx.x * 256 + threadIdx.x;
    if (i < n4) {
        floatx4 f = ((const floatx4*)in)[i];
        ushortx4 u;
        #pragma unroll
        for (int j = 0; j < 4; ++j) u[j] = f2bf(f[j]);
        ((ushortx4*)out)[i] = u;
    }
}

// ---------------- BN prep ----------------
__global__ void bn_prep(const float* __restrict__ g, const float* __restrict__ b,
                        const float* __restrict__ m, const float* __restrict__ v,
                        float* __restrict__ scale, float* __restrict__ shift, int n) {
    int i = blockIdx.x * 256 + threadIdx.x;
    if (i < n) {
        float s = g[i] * rsqrtf(v[i] + 1e-5f);
        scale[i] = s;
        shift[i] = b[i] - m[i] * s;
    }
}

// ---------------- bias table (pre-scaled by log2e): bias[h][i][j] = log2e*ab[h][idxs[i][j]]
__global__ void bias_prep(const float* __restrict__ ab, const int* __restrict__ idxs,
                          ushort_t* __restrict__ bias) {
    int tid = blockIdx.x * 256 + threadIdx.x;
    if (tid >= NH * NN * NNP) return;
    int j = tid % NNP;
    int rest = tid / NNP;
    int i = rest % NN;
    int h = rest / NN;
    float v = -43000.0f;                     // exp2 -> 0 for padded keys
    if (j < NN) v = 1.4426950408889634f * ab[h * NN + idxs[i * NN + j]];
    bias[tid] = f2bf(v);
}

// ---------------- QKV GEMM (global_load_lds staging) + BN + scatter ----
__global__ __launch_bounds__(256, 4)
void qkv_gemm(const ushort_t* __restrict__ xb, const ushort_t* __restrict__ wb,
              const float* __restrict__ scale, const float* __restrict__ shift,
              ushort_t* __restrict__ qbuf, ushort_t* __restrict__ kbuf,
              ushort_t* __restrict__ vbuf) {
    __shared__ ushort_t As[128 * 32];
    __shared__ ushort_t Bs[128 * 32];
    const int t = threadIdx.x;
    const int m0 = blockIdx.x * 128;
    const int n0 = blockIdx.y * 128;
    const int wave = t >> 6, lane = t & 63;
    const int wm = wave >> 1, wn = wave & 1;
    const int l16 = lane & 15, quad = lane >> 4;
    const int r4 = lane >> 2, c8 = lane & 3;

    floatx4 acc[4][4] = {};

    const ushort_t* agp = xb + (size_t)(m0 + wave * 16 + r4) * DIMC + c8 * 8;
    const ushort_t* bgp = wb + (size_t)(n0 + wave * 16 + r4) * DIMC + c8 * 8;
    ushort_t* alp = As + wave * 16 * 32;
    ushort_t* blp = Bs + wave * 16 * 32;

    for (int k0 = 0; k0 < DIMC; k0 += 32) {
        gld16(alp,           agp + k0);
        gld16(alp + 64 * 32, agp + (size_t)64 * DIMC + k0);
        gld16(blp,           bgp + k0);
        gld16(blp + 64 * 32, bgp + (size_t)64 * DIMC + k0);
        __syncthreads();
        shortx8 af[4], bfr[4];
        #pragma unroll
        for (int i = 0; i < 4; ++i)
            af[i] = *(const shortx8*)(As + (wm * 64 + i * 16 + l16) * 32 + quad * 8);
        #pragma unroll
        for (int j = 0; j < 4; ++j)
            bfr[j] = *(const shortx8*)(Bs + (wn * 64 + j * 16 + l16) * 32 + quad * 8);
        #pragma unroll
        for (int i = 0; i < 4; ++i)
            #pragma unroll
            for (int j = 0; j < 4; ++j)
                acc[i][j] = __builtin_amdgcn_mfma_f32_16x16x32_bf16(af[i], bfr[j], acc[i][j], 0, 0, 0);
        __syncthreads();
    }

    #pragma unroll
    for (int j = 0; j < 4; ++j) {
        const int gn = n0 + wn * 64 + j * 16 + l16;
        const float sc = scale[gn], sh = shift[gn];
        const int h = gn / 192, rr = gn % 192;
        if (rr < 2 * KD) {
            #pragma unroll
            for (int i = 0; i < 4; ++i) {
                #pragma unroll
                for (int r = 0; r < 4; ++r) {
                    const int gm = m0 + wm * 64 + i * 16 + quad * 4 + r;
                    const int bb = gm / NN, n = gm - bb * NN;
                    const ushort_t bv = f2bf(acc[i][j][r] * sc + sh);
                    const size_t bh = (size_t)bb * NH + h;
                    if (rr < KD) qbuf[(bh * NN + n) * KD + rr] = bv;
                    else         kbuf[(bh * NNP + n) * KD + (rr - KD)] = bv;
                }
            }
        } else {
            const int d = rr - 2 * KD;
            #pragma unroll
            for (int i = 0; i < 4; ++i) {
                const int gm0 = m0 + wm * 64 + i * 16 + quad * 4;
                const int bb = gm0 / NN, n = gm0 - bb * NN;
                const size_t bh = (size_t)bb * NH + h;
                ushortx4 pk;
                #pragma unroll
                for (int r = 0; r < 4; ++r) pk[r] = f2bf(acc[i][j][r] * sc + sh);
                *(ushortx4*)(vbuf + (bh * VD + d) * NNP + n) = pk;
            }
        }
    }
}

// ---------------- Attention: S^T trick, vector bias/P, pipelined K staging ------
__global__ __launch_bounds__(256, 5)
void attn_kernel(const ushort_t* __restrict__ qbuf, const ushort_t* __restrict__ kbuf,
                 const ushort_t* __restrict__ vbuf, const ushort_t* __restrict__ bias,
                 ushort_t* __restrict__ obuf) {
    __shared__ ushort_t Ks[128 * KROW];
    __shared__ ushort_t Ps[64 * PROW];
    __shared__ float linv[64];

    const int t = threadIdx.x;
    const int wave = t >> 6, lane = t & 63;
    const int l16 = lane & 15, quad = lane >> 4;
    const int bid = blockIdx.x;
    const int b = bid & 31;
    const int hq = bid >> 5;
    const int h = hq & 7;
    const int qt = hq >> 3;            // 0..12
    const int bh = b * NH + h;
    const int i0 = qt * 64;
    const int mvalid = min(4, (NN - i0 + 15) >> 4);
    const bool swave = wave < mvalid;
    const float SC2 = 0.25505679f;     // (1/sqrt(32)) * log2(e)

    const ushort_t* qbase = qbuf + ((size_t)bh * NN + i0) * KD;
    const ushort_t* kbase = kbuf + (size_t)bh * NNP * KD;
    const ushort_t* vbase = vbuf + (size_t)bh * VD * NNP;
    const ushort_t* bbase = bias + ((size_t)h * NN + i0) * NNP;

    // Q is the B-operand of S^T: B[n=qrow(l16)][k=d(quad*8+j)]
    shortx8 qf = {};
    if (swave) qf = *(const shortx8*)(qbase + (wave * 16 + l16) * KD + quad * 8);

    float lacc = 0.0f;
    floatx4 oacc[4][2] = {};

    // K staging: 4 threads/row, 16B each; software-pipelined via kr0/kr1
    const int srow = t >> 2, sq4 = t & 3;
    const ushort_t* kstage = kbase + (size_t)srow * KD + sq4 * 8;
    ushort_t* kdst0 = Ks + srow * KROW + sq4 * 8;
    ushort_t* kdst1 = Ks + (64 + srow) * KROW + sq4 * 8;

    uintx4 kr0 = *(const uintx4*)(kstage);
    uintx4 kr1 = *(const uintx4*)(kstage + (size_t)64 * KD);
    *(uintx4*)kdst0 = kr0;
    *(uintx4*)kdst1 = kr1;
    kr0 = *(const uintx4*)(kstage + (size_t)128 * KD);
    kr1 = *(const uintx4*)(kstage + (size_t)192 * KD);
    __syncthreads();

    const int myrow = wave * 16 + l16;                        // qrow in [0,64)
    const ushort_t* brow = bbase + (size_t)myrow * NNP + quad * 4;
    ushort_t* prow = Ps + myrow * PROW + quad * 4;

    for (int c = 0; c < 7; ++c) {
        // ---- S^T phase: lane holds (qrow=l16, 4 consecutive keys=quad*4+r) ----
        if (swave) {
            #pragma unroll
            for (int kt = 0; kt < 8; ++kt) {
                shortx8 kf = *(const shortx8*)(Ks + (kt * 16 + l16) * KROW + quad * 8);
                floatx4 d = {};
                d = __builtin_amdgcn_mfma_f32_16x16x32_bf16(kf, qf, d, 0, 0, 0);
                ushortx4 bv = *(const ushortx4*)(brow + c * 128 + kt * 16);
                ushortx4 pv;
                #pragma unroll
                for (int r = 0; r < 4; ++r) {
                    const float e = exp2f(fmaf(d[r], SC2, bf2f(bv[r])));
                    lacc += e;
                    pv[r] = f2bf(e);
                }
                *(ushortx4*)(prow + kt * 16) = pv;            // ds_write_b64, 2-way (free)
            }
        }
        __syncthreads();   // Ps(c) visible; Ks(c) fully consumed

        // ---- stage K(c+1) from regs; prefetch K(c+2) ----
        if (c < 6) {
            *(uintx4*)kdst0 = kr0;
            *(uintx4*)kdst1 = kr1;
            if (c < 5) {
                kr0 = *(const uintx4*)(kstage + (size_t)(c + 2) * 128 * KD);
                kr1 = *(const uintx4*)(kstage + ((size_t)(c + 2) * 128 + 64) * KD);
            }
        }

        // ---- PV phase: wave -> vd cols [32w, 32w+32) for all m ----
        {
            const ushort_t* vb = vbase + (size_t)(wave * 32) * NNP + c * 128;
            #pragma unroll
            for (int ks = 0; ks < 4; ++ks) {
                shortx8 v0 = *(const shortx8*)(vb + (size_t)l16 * NNP + ks * 32 + quad * 8);
                shortx8 v1 = *(const shortx8*)(vb + (size_t)(16 + l16) * NNP + ks * 32 + quad * 8);
                #pragma unroll
                for (int ms = 0; ms < 4; ++ms) {
                    if (ms < mvalid) {
                        shortx8 af = *(const shortx8*)(Ps + (ms * 16 + l16) * PROW + ks * 32 + quad * 8);
                        oacc[ms][0] = __builtin_amdgcn_mfma_f32_16x16x32_bf16(af, v0, oacc[ms][0], 0, 0, 0);
                        oacc[ms][1] = __builtin_amdgcn_mfma_f32_16x16x32_bf16(af, v1, oacc[ms][1], 0, 0, 0);
                    }
                }
            }
        }
        __syncthreads();   // PV(c) done: Ps free for next S; Ks(c+1) visible
    }

    // ---- row sums: reduce across quads (lanes sharing l16) ----
    if (swave) {
        float s = lacc;
        s += __shfl_xor(s, 16);
        s += __shfl_xor(s, 32);
        if (quad == 0) linv[myrow] = 1.0f / s;
    }
    __syncthreads();

    // ---- epilogue: normalize, hardswish, store ----
    #pragma unroll
    for (int ms = 0; ms < 4; ++ms) {
        if (ms < mvalid) {
            #pragma unroll
            for (int vt = 0; vt < 2; ++vt) {
                const int vd = h * VD + wave * 32 + vt * 16 + l16;
                #pragma unroll
                for (int r = 0; r < 4; ++r) {
                    const int row = i0 + ms * 16 + quad * 4 + r;
                    const float o = oacc[ms][vt][r] * linv[ms * 16 + quad * 4 + r];
                    const float hs = o * fminf(fmaxf(o + 3.0f, 0.0f), 6.0f) * (1.0f / 6.0f);
                    obuf[((size_t)b * NN + row) * VAL_ATTN + vd] = f2bf(hs);
                }
            }
        }
    }
}

// ---------------- Proj GEMM (global_load_lds staging) + BN -> fp32 ------
__global__ __launch_bounds__(256, 4)
void proj_gemm(const ushort_t* __restrict__ obuf, const ushort_t* __restrict__ pwb,
               const float* __restrict__ pscale, const float* __restrict__ pshift,
               float* __restrict__ out) {
    __shared__ ushort_t As[128 * 32];
    __shared__ ushort_t Bs[128 * 32];
    const int t = threadIdx.x;
    const int m0 = blockIdx.x * 128;
    const int n0 = blockIdx.y * 128;
    const int wave = t >> 6, lane = t & 63;
    const int wm = wave >> 1, wn = wave & 1;
    const int l16 = lane & 15, quad = lane >> 4;
    const int r4 = lane >> 2, c8 = lane & 3;

    floatx4 acc[4][4] = {};

    const ushort_t* agp = obuf + (size_t)(m0 + wave * 16 + r4) * VAL_ATTN + c8 * 8;
    const ushort_t* bgp = pwb + (size_t)(n0 + wave * 16 + r4) * VAL_ATTN + c8 * 8;
    ushort_t* alp = As + wave * 16 * 32;
    ushort_t* blp = Bs + wave * 16 * 32;

    for (int k0 = 0; k0 < VAL_ATTN; k0 += 32) {
        gld16(alp,           agp + k0);
        gld16(alp + 64 * 32, agp + (size_t)64 * VAL_ATTN + k0);
        gld16(blp,           bgp + k0);
        gld16(blp + 64 * 32, bgp + (size_t)64 * VAL_ATTN + k0);
        __syncthreads();
        shortx8 af[4], bfr[4];
        #pragma unroll
        for (int i = 0; i < 4; ++i)
            af[i] = *(const shortx8*)(As + (wm * 64 + i * 16 + l16) * 32 + quad * 8);
        #pragma unroll
        for (int j = 0; j < 4; ++j)
            bfr[j] = *(const shortx8*)(Bs + (wn * 64 + j * 16 + l16) * 32 + quad * 8);
        #pragma unroll
        for (int i = 0; i < 4; ++i)
            #pragma unroll
            for (int j = 0; j < 4; ++j)
                acc[i][j] = __builtin_amdgcn_mfma_f32_16x16x32_bf16(af[i], bfr[j], acc[i][j], 0, 0, 0);
        __syncthreads();
    }

    #pragma unroll
    for (int j = 0; j < 4; ++j) {
        const int gn = n0 + wn * 64 + j * 16 + l16;
        const float sc = pscale[gn], sh = pshift[gn];
        #pragma unroll
        for (int i = 0; i < 4; ++i) {
            #pragma unroll
            for (int r = 0; r < 4; ++r) {
                const int gm = m0 + wm * 64 + i * 16 + quad * 4 + r;
                out[(size_t)gm * DIMC + gn] = acc[i][j][r] * sc + sh;
            }
        }
    }
}

extern "C" void kernel_launch(void* const* d_in, const int* in_sizes, int n_in,
                              void* d_out, int out_size, void* d_ws, size_t ws_size,
                              hipStream_t stream) {
    const float* x      = (const float*)d_in[0];
    const float* qkv_w  = (const float*)d_in[1];
    const float* qkv_g  = (const float*)d_in[2];
    const float* qkv_b  = (const float*)d_in[3];
    const float* qkv_m  = (const float*)d_in[4];
    const float* qkv_v  = (const float*)d_in[5];
    const float* ab     = (const float*)d_in[6];
    const float* proj_w = (const float*)d_in[7];
    const float* proj_g = (const float*)d_in[8];
    const float* proj_b = (const float*)d_in[9];
    const float* proj_m = (const float*)d_in[10];
    const float* proj_v = (const float*)d_in[11];
    const int*   idxs   = (const int*)d_in[12];
    float* out = (float*)d_out;

    char* ws = (char*)d_ws;
    size_t off = 0;
    auto alloc = [&](size_t bytes) {
        void* p = ws + off;
        off = (off + bytes + 255) & ~(size_t)255;
        return p;
    };
    ushort_t* qbuf = (ushort_t*)alloc((size_t)NB * NH * NN * KD * 2);
    ushort_t* kbuf = (ushort_t*)alloc((size_t)NB * NH * NNP * KD * 2);
    ushort_t* vbuf = (ushort_t*)alloc((size_t)NB * NH * VD * NNP * 2);
    ushort_t* obuf = (ushort_t*)alloc((size_t)NB * NN * VAL_ATTN * 2);
    ushort_t* bias = (ushort_t*)alloc((size_t)NH * NN * NNP * 2);
    ushort_t* xb   = (ushort_t*)alloc((size_t)NB * NN * DIMC * 2);
    ushort_t* wqb  = (ushort_t*)alloc((size_t)QKV_OUT * DIMC * 2);
    ushort_t* pwb  = (ushort_t*)alloc((size_t)DIMC * VAL_ATTN * 2);
    float* qscale = (float*)alloc(QKV_OUT * 4);
    float* qshift = (float*)alloc(QKV_OUT * 4);
    float* pscale = (float*)alloc(DIMC * 4);
    float* pshift = (float*)alloc(DIMC * 4);

    const int nx4 = NB * NN * DIMC / 4;
    const int nw4 = QKV_OUT * DIMC / 4;
    const int np4 = DIMC * VAL_ATTN / 4;
    cvt_bf16<<<(nx4 + 255) / 256, 256, 0, stream>>>(x, xb, nx4);
    cvt_bf16<<<(nw4 + 255) / 256, 256, 0, stream>>>(qkv_w, wqb, nw4);
    cvt_bf16<<<(np4 + 255) / 256, 256, 0, stream>>>(proj_w, pwb, np4);
    bn_prep<<<6, 256, 0, stream>>>(qkv_g, qkv_b, qkv_m, qkv_v, qscale, qshift, QKV_OUT);
    bn_prep<<<2, 256, 0, stream>>>(proj_g, proj_b, proj_m, proj_v, pscale, pshift, DIMC);
    bias_prep<<<(NH * NN * NNP + 255) / 256, 256, 0, stream>>>(ab, idxs, bias);
    qkv_gemm<<<dim3(196, 12), 256, 0, stream>>>(xb, wqb, qscale, qshift, qbuf, kbuf, vbuf);
    attn_kernel<<<dim3(32 * NH * 13), 256, 0, stream>>>(qbuf, kbuf, vbuf, bias, obuf);
    proj_gemm<<<dim3(196, 4), 256, 0, stream>>>(obuf, pwb, pscale, pshift, out);
}

// Round 5
// 434.306 us; speedup vs baseline: 1.0106x; 1.0106x over previous
//
#include <hip/hip_runtime.h>
#include <hip/hip_bf16.h>

#define NB 32
#define NN 784
#define NNP 896        // N padded to 7*128 k-chunks
#define DIMC 512
#define NH 8
#define KD 32
#define VD 128
#define QKV_OUT 1536
#define VAL_ATTN 1024
#define PROW 136       // P LDS row stride (ushorts) -> bank-uniform for b64 writes / b128 reads
#define KROW 40        // K LDS row stride (ushorts) -> bank-uniform for b128 reads

typedef __attribute__((ext_vector_type(4))) float floatx4;
typedef __attribute__((ext_vector_type(8))) short shortx8;
typedef __attribute__((ext_vector_type(4))) unsigned short ushortx4;
typedef __attribute__((ext_vector_type(4))) unsigned int uintx4;
typedef unsigned short ushort_t;

__device__ __forceinline__ unsigned short f2bf(float f) {
    union { float f; unsigned int u; } v; v.f = f;
    unsigned int r = v.u + 0x7fffu + ((v.u >> 16) & 1u);
    return (unsigned short)(r >> 16);
}
__device__ __forceinline__ float bf2f(unsigned short s) {
    union { unsigned int u; float f; } v; v.u = ((unsigned int)s) << 16;
    return v.f;
}
__device__ __forceinline__ void gld16(void* lds, const void* g) {
    __builtin_amdgcn_global_load_lds((const __attribute__((address_space(1))) void*)g,
                                     (__attribute__((address_space(3))) void*)lds, 16, 0, 0);
}

// ---------------- fp32 -> bf16 bulk convert ----------------
__global__ void cvt_bf16(const float* __restrict__ in, ushort_t* __restrict__ out, int n4) {
    int i = blockIdx.x * 256 + threadIdx.x;
    if (i < n4) {
        floatx4 f = ((const floatx4*)in)[i];
        ushortx4 u;
        #pragma unroll
        for (int j = 0; j < 4; ++j) u[j] = f2bf(f[j]);
        ((ushortx4*)out)[i] = u;
    }
}

// ---------------- BN prep ----------------
__global__ void bn_prep(const float* __restrict__ g, const float* __restrict__ b,
                        const float* __restrict__ m, const float* __restrict__ v,
                        float* __restrict__ scale, float* __restrict__ shift, int n) {
    int i = blockIdx.x * 256 + threadIdx.x;
    if (i < n) {
        float s = g[i] * rsqrtf(v[i] + 1e-5f);
        scale[i] = s;
        shift[i] = b[i] - m[i] * s;
    }
}

// ---------------- bias table (pre-scaled by log2e): bias[h][i][j] = log2e*ab[h][idxs[i][j]]
__global__ void bias_prep(const float* __restrict__ ab, const int* __restrict__ idxs,
                          ushort_t* __restrict__ bias) {
    int tid = blockIdx.x * 256 + threadIdx.x;
    if (tid >= NH * NN * NNP) return;
    int j = tid % NNP;
    int rest = tid / NNP;
    int i = rest % NN;
    int h = rest / NN;
    float v = -43000.0f;                     // exp2 -> 0 for padded keys
    if (j < NN) v = 1.4426950408889634f * ab[h * NN + idxs[i * NN + j]];
    bias[tid] = f2bf(v);
}

// ---------------- QKV GEMM (global_load_lds staging) + BN + scatter ----
__global__ __launch_bounds__(256, 4)
void qkv_gemm(const ushort_t* __restrict__ xb, const ushort_t* __restrict__ wb,
              const float* __restrict__ scale, const float* __restrict__ shift,
              ushort_t* __restrict__ qbuf, ushort_t* __restrict__ kbuf,
              ushort_t* __restrict__ vbuf) {
    __shared__ ushort_t As[128 * 32];
    __shared__ ushort_t Bs[128 * 32];
    const int t = threadIdx.x;
    const int m0 = blockIdx.x * 128;
    const int n0 = blockIdx.y * 128;
    const int wave = t >> 6, lane = t & 63;
    const int wm = wave >> 1, wn = wave & 1;
    const int l16 = lane & 15, quad = lane >> 4;
    const int r4 = lane >> 2, c8 = lane & 3;

    floatx4 acc[4][4] = {};

    const ushort_t* agp = xb + (size_t)(m0 + wave * 16 + r4) * DIMC + c8 * 8;
    const ushort_t* bgp = wb + (size_t)(n0 + wave * 16 + r4) * DIMC + c8 * 8;
    ushort_t* alp = As + wave * 16 * 32;
    ushort_t* blp = Bs + wave * 16 * 32;

    for (int k0 = 0; k0 < DIMC; k0 += 32) {
        gld16(alp,           agp + k0);
        gld16(alp + 64 * 32, agp + (size_t)64 * DIMC + k0);
        gld16(blp,           bgp + k0);
        gld16(blp + 64 * 32, bgp + (size_t)64 * DIMC + k0);
        __syncthreads();
        shortx8 af[4], bfr[4];
        #pragma unroll
        for (int i = 0; i < 4; ++i)
            af[i] = *(const shortx8*)(As + (wm * 64 + i * 16 + l16) * 32 + quad * 8);
        #pragma unroll
        for (int j = 0; j < 4; ++j)
            bfr[j] = *(const shortx8*)(Bs + (wn * 64 + j * 16 + l16) * 32 + quad * 8);
        #pragma unroll
        for (int i = 0; i < 4; ++i)
            #pragma unroll
            for (int j = 0; j < 4; ++j)
                acc[i][j] = __builtin_amdgcn_mfma_f32_16x16x32_bf16(af[i], bfr[j], acc[i][j], 0, 0, 0);
        __syncthreads();
    }

    #pragma unroll
    for (int j = 0; j < 4; ++j) {
        const int gn = n0 + wn * 64 + j * 16 + l16;
        const float sc = scale[gn], sh = shift[gn];
        const int h = gn / 192, rr = gn % 192;
        if (rr < 2 * KD) {
            #pragma unroll
            for (int i = 0; i < 4; ++i) {
                #pragma unroll
                for (int r = 0; r < 4; ++r) {
                    const int gm = m0 + wm * 64 + i * 16 + quad * 4 + r;
                    const int bb = gm / NN, n = gm - bb * NN;
                    const ushort_t bv = f2bf(acc[i][j][r] * sc + sh);
                    const size_t bh = (size_t)bb * NH + h;
                    if (rr < KD) qbuf[(bh * NN + n) * KD + rr] = bv;
                    else         kbuf[(bh * NNP + n) * KD + (rr - KD)] = bv;
                }
            }
        } else {
            const int d = rr - 2 * KD;
            #pragma unroll
            for (int i = 0; i < 4; ++i) {
                const int gm0 = m0 + wm * 64 + i * 16 + quad * 4;
                const int bb = gm0 / NN, n = gm0 - bb * NN;
                const size_t bh = (size_t)bb * NH + h;
                ushortx4 pk;
                #pragma unroll
                for (int r = 0; r < 4; ++r) pk[r] = f2bf(acc[i][j][r] * sc + sh);
                *(ushortx4*)(vbuf + (bh * VD + d) * NNP + n) = pk;
            }
        }
    }
}

// ---------------- Attention: S^T layout, vector bias/P ops, simple 2-sync loop ---
__global__ __launch_bounds__(256, 4)
void attn_kernel(const ushort_t* __restrict__ qbuf, const ushort_t* __restrict__ kbuf,
                 const ushort_t* __restrict__ vbuf, const ushort_t* __restrict__ bias,
                 ushort_t* __restrict__ obuf) {
    __shared__ ushort_t Ks[128 * KROW];
    __shared__ ushort_t Ps[64 * PROW];
    __shared__ float linv[64];

    const int t = threadIdx.x;
    const int wave = t >> 6, lane = t & 63;
    const int l16 = lane & 15, quad = lane >> 4;
    const int bid = blockIdx.x;
    const int b = bid & 31;
    const int hq = bid >> 5;
    const int h = hq & 7;
    const int qt = hq >> 3;            // 0..12
    const int bh = b * NH + h;
    const int i0 = qt * 64;
    const int mvalid = min(4, (NN - i0 + 15) >> 4);
    const bool swave = wave < mvalid;
    const float SC2 = 0.25505679f;     // (1/sqrt(32)) * log2(e)

    const ushort_t* qbase = qbuf + ((size_t)bh * NN + i0) * KD;
    const ushort_t* kbase = kbuf + (size_t)bh * NNP * KD;
    const ushort_t* vbase = vbuf + (size_t)bh * VD * NNP;
    const ushort_t* bbase = bias + ((size_t)h * NN + i0) * NNP;

    // Q as B-operand of S^T: B[n=qrow(l16)][k=d(quad*8+j)]
    shortx8 qf = {};
    if (swave) qf = *(const shortx8*)(qbase + (wave * 16 + l16) * KD + quad * 8);

    float lacc = 0.0f;
    floatx4 oacc[4][2] = {};

    const int srow = t >> 2, sq4 = t & 3;
    const int myrow = wave * 16 + l16;                        // qrow in [0,64)
    const ushort_t* brow = bbase + (size_t)myrow * NNP + quad * 4;
    ushort_t* prow = Ps + myrow * PROW + quad * 4;

    for (int c = 0; c < 7; ++c) {
        // ---- stage K chunk (128 x 32 bf16) ----
        #pragma unroll
        for (int rr = 0; rr < 2; ++rr) {
            const int row = rr * 64 + srow;
            *(uintx4*)(Ks + row * KROW + sq4 * 8) =
                *(const uintx4*)(kbase + (size_t)(c * 128 + row) * KD + sq4 * 8);
        }
        __syncthreads();

        // ---- S^T phase: lane holds (qrow=l16, 4 consecutive keys=quad*4+r) ----
        if (swave) {
            #pragma unroll
            for (int kt = 0; kt < 8; ++kt) {
                shortx8 kf = *(const shortx8*)(Ks + (kt * 16 + l16) * KROW + quad * 8);
                floatx4 d = {};
                d = __builtin_amdgcn_mfma_f32_16x16x32_bf16(kf, qf, d, 0, 0, 0);
                ushortx4 bv = *(const ushortx4*)(brow + c * 128 + kt * 16);
                ushortx4 pv;
                #pragma unroll
                for (int r = 0; r < 4; ++r) {
                    const float e = __builtin_amdgcn_exp2f(fmaf(d[r], SC2, bf2f(bv[r])));
                    lacc += e;
                    pv[r] = f2bf(e);
                }
                *(ushortx4*)(prow + kt * 16) = pv;            // ds_write_b64, bank-uniform
            }
        }
        __syncthreads();

        // ---- PV phase: wave -> vd cols [32w, 32w+32) for all m ----
        {
            const ushort_t* vb = vbase + (size_t)(wave * 32) * NNP + c * 128;
            #pragma unroll
            for (int ks = 0; ks < 4; ++ks) {
                shortx8 v0 = *(const shortx8*)(vb + (size_t)l16 * NNP + ks * 32 + quad * 8);
                shortx8 v1 = *(const shortx8*)(vb + (size_t)(16 + l16) * NNP + ks * 32 + quad * 8);
                #pragma unroll
                for (int ms = 0; ms < 4; ++ms) {
                    if (ms < mvalid) {
                        shortx8 af = *(const shortx8*)(Ps + (ms * 16 + l16) * PROW + ks * 32 + quad * 8);
                        oacc[ms][0] = __builtin_amdgcn_mfma_f32_16x16x32_bf16(af, v0, oacc[ms][0], 0, 0, 0);
                        oacc[ms][1] = __builtin_amdgcn_mfma_f32_16x16x32_bf16(af, v1, oacc[ms][1], 0, 0, 0);
                    }
                }
            }
        }
    }

    // ---- row sums: reduce across quads (lanes sharing l16) ----
    if (swave) {
        float s = lacc;
        s += __shfl_xor(s, 16);
        s += __shfl_xor(s, 32);
        if (quad == 0) linv[myrow] = 1.0f / s;
    }
    __syncthreads();

    // ---- epilogue: normalize, hardswish, store ----
    #pragma unroll
    for (int ms = 0; ms < 4; ++ms) {
        if (ms < mvalid) {
            #pragma unroll
            for (int vt = 0; vt < 2; ++vt) {
                const int vd = h * VD + wave * 32 + vt * 16 + l16;
                #pragma unroll
                for (int r = 0; r < 4; ++r) {
                    const int row = i0 + ms * 16 + quad * 4 + r;
                    const float o = oacc[ms][vt][r] * linv[ms * 16 + quad * 4 + r];
                    const float hs = o * fminf(fmaxf(o + 3.0f, 0.0f), 6.0f) * (1.0f / 6.0f);
                    obuf[((size_t)b * NN + row) * VAL_ATTN + vd] = f2bf(hs);
                }
            }
        }
    }
}

// ---------------- Proj GEMM (global_load_lds staging) + BN -> fp32 ------
__global__ __launch_bounds__(256, 4)
void proj_gemm(const ushort_t* __restrict__ obuf, const ushort_t* __restrict__ pwb,
               const float* __restrict__ pscale, const float* __restrict__ pshift,
               float* __restrict__ out) {
    __shared__ ushort_t As[128 * 32];
    __shared__ ushort_t Bs[128 * 32];
    const int t = threadIdx.x;
    const int m0 = blockIdx.x * 128;
    const int n0 = blockIdx.y * 128;
    const int wave = t >> 6, lane = t & 63;
    const int wm = wave >> 1, wn = wave & 1;
    const int l16 = lane & 15, quad = lane >> 4;
    const int r4 = lane >> 2, c8 = lane & 3;

    floatx4 acc[4][4] = {};

    const ushort_t* agp = obuf + (size_t)(m0 + wave * 16 + r4) * VAL_ATTN + c8 * 8;
    const ushort_t* bgp = pwb + (size_t)(n0 + wave * 16 + r4) * VAL_ATTN + c8 * 8;
    ushort_t* alp = As + wave * 16 * 32;
    ushort_t* blp = Bs + wave * 16 * 32;

    for (int k0 = 0; k0 < VAL_ATTN; k0 += 32) {
        gld16(alp,           agp + k0);
        gld16(alp + 64 * 32, agp + (size_t)64 * VAL_ATTN + k0);
        gld16(blp,           bgp + k0);
        gld16(blp + 64 * 32, bgp + (size_t)64 * VAL_ATTN + k0);
        __syncthreads();
        shortx8 af[4], bfr[4];
        #pragma unroll
        for (int i = 0; i < 4; ++i)
            af[i] = *(const shortx8*)(As + (wm * 64 + i * 16 + l16) * 32 + quad * 8);
        #pragma unroll
        for (int j = 0; j < 4; ++j)
            bfr[j] = *(const shortx8*)(Bs + (wn * 64 + j * 16 + l16) * 32 + quad * 8);
        #pragma unroll
        for (int i = 0; i < 4; ++i)
            #pragma unroll
            for (int j = 0; j < 4; ++j)
                acc[i][j] = __builtin_amdgcn_mfma_f32_16x16x32_bf16(af[i], bfr[j], acc[i][j], 0, 0, 0);
        __syncthreads();
    }

    #pragma unroll
    for (int j = 0; j < 4; ++j) {
        const int gn = n0 + wn * 64 + j * 16 + l16;
        const float sc = pscale[gn], sh = pshift[gn];
        #pragma unroll
        for (int i = 0; i < 4; ++i) {
            #pragma unroll
            for (int r = 0; r < 4; ++r) {
                const int gm = m0 + wm * 64 + i * 16 + quad * 4 + r;
                out[(size_t)gm * DIMC + gn] = acc[i][j][r] * sc + sh;
            }
        }
    }
}

extern "C" void kernel_launch(void* const* d_in, const int* in_sizes, int n_in,
                              void* d_out, int out_size, void* d_ws, size_t ws_size,
                              hipStream_t stream) {
    const float* x      = (const float*)d_in[0];
    const float* qkv_w  = (const float*)d_in[1];
    const float* qkv_g  = (const float*)d_in[2];
    const float* qkv_b  = (const float*)d_in[3];
    const float* qkv_m  = (const float*)d_in[4];
    const float* qkv_v  = (const float*)d_in[5];
    const float* ab     = (const float*)d_in[6];
    const float* proj_w = (const float*)d_in[7];
    const float* proj_g = (const float*)d_in[8];
    const float* proj_b = (const float*)d_in[9];
    const float* proj_m = (const float*)d_in[10];
    const float* proj_v = (const float*)d_in[11];
    const int*   idxs   = (const int*)d_in[12];
    float* out = (float*)d_out;

    char* ws = (char*)d_ws;
    size_t off = 0;
    auto alloc = [&](size_t bytes) {
        void* p = ws + off;
        off = (off + bytes + 255) & ~(size_t)255;
        return p;
    };
    ushort_t* qbuf = (ushort_t*)alloc((size_t)NB * NH * NN * KD * 2);
    ushort_t* kbuf = (ushort_t*)alloc((size_t)NB * NH * NNP * KD * 2);
    ushort_t* vbuf = (ushort_t*)alloc((size_t)NB * NH * VD * NNP * 2);
    ushort_t* obuf = (ushort_t*)alloc((size_t)NB * NN * VAL_ATTN * 2);
    ushort_t* bias = (ushort_t*)alloc((size_t)NH * NN * NNP * 2);
    ushort_t* xb   = (ushort_t*)alloc((size_t)NB * NN * DIMC * 2);
    ushort_t* wqb  = (ushort_t*)alloc((size_t)QKV_OUT * DIMC * 2);
    ushort_t* pwb  = (ushort_t*)alloc((size_t)DIMC * VAL_ATTN * 2);
    float* qscale = (float*)alloc(QKV_OUT * 4);
    float* qshift = (float*)alloc(QKV_OUT * 4);
    float* pscale = (float*)alloc(DIMC * 4);
    float* pshift = (float*)alloc(DIMC * 4);

    const int nx4 = NB * NN * DIMC / 4;
    const int nw4 = QKV_OUT * DIMC / 4;
    const int np4 = DIMC * VAL_ATTN / 4;
    cvt_bf16<<<(nx4 + 255) / 256, 256, 0, stream>>>(x, xb, nx4);
    cvt_bf16<<<(nw4 + 255) / 256, 256, 0, stream>>>(qkv_w, wqb, nw4);
    cvt_bf16<<<(np4 + 255) / 256, 256, 0, stream>>>(proj_w, pwb, np4);
    bn_prep<<<6, 256, 0, stream>>>(qkv_g, qkv_b, qkv_m, qkv_v, qscale, qshift, QKV_OUT);
    bn_prep<<<2, 256, 0, stream>>>(proj_g, proj_b, proj_m, proj_v, pscale, pshift, DIMC);
    bias_prep<<<(NH * NN * NNP + 255) / 256, 256, 0, stream>>>(ab, idxs, bias);
    qkv_gemm<<<dim3(196, 12), 256, 0, stream>>>(xb, wqb, qscale, qshift, qbuf, kbuf, vbuf);
    attn_kernel<<<dim3(32 * NH * 13), 256, 0, stream>>>(qbuf, kbuf, vbuf, bias, obuf);
    proj_gemm<<<dim3(196, 4), 256, 0, stream>>>(obuf, pwb, pscale, pshift, out);
}

// Round 6
// 396.040 us; speedup vs baseline: 1.1082x; 1.0966x over previous
//
#include <hip/hip_runtime.h>
#include <hip/hip_bf16.h>

#define NB 32
#define NN 784
#define NNP 896        // N padded to 7*128 k-chunks
#define DIMC 512
#define NH 8
#define KD 32
#define VD 128
#define QKV_OUT 1536
#define VAL_ATTN 1024
#define PROW 136       // P LDS row stride (ushorts) — R3-proven
#define KROW 32        // K LDS row stride: unpadded (required by global_load_lds layout)

typedef __attribute__((ext_vector_type(4))) float floatx4;
typedef __attribute__((ext_vector_type(8))) short shortx8;
typedef __attribute__((ext_vector_type(4))) unsigned short ushortx4;
typedef __attribute__((ext_vector_type(4))) unsigned int uintx4;
typedef unsigned short ushort_t;

__device__ __forceinline__ unsigned short f2bf(float f) {
    union { float f; unsigned int u; } v; v.f = f;
    unsigned int r = v.u + 0x7fffu + ((v.u >> 16) & 1u);
    return (unsigned short)(r >> 16);
}
__device__ __forceinline__ float bf2f(unsigned short s) {
    union { unsigned int u; float f; } v; v.u = ((unsigned int)s) << 16;
    return v.f;
}
__device__ __forceinline__ void gld16(void* lds, const void* g) {
    __builtin_amdgcn_global_load_lds((const __attribute__((address_space(1))) void*)g,
                                     (__attribute__((address_space(3))) void*)lds, 16, 0, 0);
}

// ---------------- fp32 -> bf16 bulk convert ----------------
__global__ void cvt_bf16(const float* __restrict__ in, ushort_t* __restrict__ out, int n4) {
    int i = blockIdx.x * 256 + threadIdx.x;
    if (i < n4) {
        floatx4 f = ((const floatx4*)in)[i];
        ushortx4 u;
        #pragma unroll
        for (int j = 0; j < 4; ++j) u[j] = f2bf(f[j]);
        ((ushortx4*)out)[i] = u;
    }
}

// ---------------- BN prep ----------------
__global__ void bn_prep(const float* __restrict__ g, const float* __restrict__ b,
                        const float* __restrict__ m, const float* __restrict__ v,
                        float* __restrict__ scale, float* __restrict__ shift, int n) {
    int i = blockIdx.x * 256 + threadIdx.x;
    if (i < n) {
        float s = g[i] * rsqrtf(v[i] + 1e-5f);
        scale[i] = s;
        shift[i] = b[i] - m[i] * s;
    }
}

// ---------------- bias table (pre-scaled by log2e): bias[h][i][j] = log2e*ab[h][idxs[i][j]]
__global__ void bias_prep(const float* __restrict__ ab, const int* __restrict__ idxs,
                          ushort_t* __restrict__ bias) {
    int tid = blockIdx.x * 256 + threadIdx.x;
    if (tid >= NH * NN * NNP) return;
    int j = tid % NNP;
    int rest = tid / NNP;
    int i = rest % NN;
    int h = rest / NN;
    float v = -43000.0f;                     // exp2 -> 0 for padded keys
    if (j < NN) v = 1.4426950408889634f * ab[h * NN + idxs[i * NN + j]];
    bias[tid] = f2bf(v);
}

// ---------------- QKV GEMM (global_load_lds staging) + BN + scatter ----
__global__ __launch_bounds__(256, 4)
void qkv_gemm(const ushort_t* __restrict__ xb, const ushort_t* __restrict__ wb,
              const float* __restrict__ scale, const float* __restrict__ shift,
              ushort_t* __restrict__ qbuf, ushort_t* __restrict__ kbuf,
              ushort_t* __restrict__ vbuf) {
    __shared__ ushort_t As[128 * 32];
    __shared__ ushort_t Bs[128 * 32];
    const int t = threadIdx.x;
    const int m0 = blockIdx.x * 128;
    const int n0 = blockIdx.y * 128;
    const int wave = t >> 6, lane = t & 63;
    const int wm = wave >> 1, wn = wave & 1;
    const int l16 = lane & 15, quad = lane >> 4;
    const int r4 = lane >> 2, c8 = lane & 3;

    floatx4 acc[4][4] = {};

    const ushort_t* agp = xb + (size_t)(m0 + wave * 16 + r4) * DIMC + c8 * 8;
    const ushort_t* bgp = wb + (size_t)(n0 + wave * 16 + r4) * DIMC + c8 * 8;
    ushort_t* alp = As + wave * 16 * 32;
    ushort_t* blp = Bs + wave * 16 * 32;

    for (int k0 = 0; k0 < DIMC; k0 += 32) {
        gld16(alp,           agp + k0);
        gld16(alp + 64 * 32, agp + (size_t)64 * DIMC + k0);
        gld16(blp,           bgp + k0);
        gld16(blp + 64 * 32, bgp + (size_t)64 * DIMC + k0);
        __syncthreads();
        shortx8 af[4], bfr[4];
        #pragma unroll
        for (int i = 0; i < 4; ++i)
            af[i] = *(const shortx8*)(As + (wm * 64 + i * 16 + l16) * 32 + quad * 8);
        #pragma unroll
        for (int j = 0; j < 4; ++j)
            bfr[j] = *(const shortx8*)(Bs + (wn * 64 + j * 16 + l16) * 32 + quad * 8);
        #pragma unroll
        for (int i = 0; i < 4; ++i)
            #pragma unroll
            for (int j = 0; j < 4; ++j)
                acc[i][j] = __builtin_amdgcn_mfma_f32_16x16x32_bf16(af[i], bfr[j], acc[i][j], 0, 0, 0);
        __syncthreads();
    }

    #pragma unroll
    for (int j = 0; j < 4; ++j) {
        const int gn = n0 + wn * 64 + j * 16 + l16;
        const float sc = scale[gn], sh = shift[gn];
        const int h = gn / 192, rr = gn % 192;
        if (rr < 2 * KD) {
            #pragma unroll
            for (int i = 0; i < 4; ++i) {
                #pragma unroll
                for (int r = 0; r < 4; ++r) {
                    const int gm = m0 + wm * 64 + i * 16 + quad * 4 + r;
                    const int bb = gm / NN, n = gm - bb * NN;
                    const ushort_t bv = f2bf(acc[i][j][r] * sc + sh);
                    const size_t bh = (size_t)bb * NH + h;
                    if (rr < KD) qbuf[(bh * NN + n) * KD + rr] = bv;
                    else         kbuf[(bh * NNP + n) * KD + (rr - KD)] = bv;
                }
            }
        } else {
            const int d = rr - 2 * KD;
            #pragma unroll
            for (int i = 0; i < 4; ++i) {
                const int gm0 = m0 + wm * 64 + i * 16 + quad * 4;
                const int bb = gm0 / NN, n = gm0 - bb * NN;
                const size_t bh = (size_t)bb * NH + h;
                ushortx4 pk;
                #pragma unroll
                for (int r = 0; r < 4; ++r) pk[r] = f2bf(acc[i][j][r] * sc + sh);
                *(ushortx4*)(vbuf + (bh * VD + d) * NNP + n) = pk;
            }
        }
    }
}

// ---------------- Attention: R3 structure + async K staging hidden behind PV ----
__global__ __launch_bounds__(256, 4)
void attn_kernel(const ushort_t* __restrict__ qbuf, const ushort_t* __restrict__ kbuf,
                 const ushort_t* __restrict__ vbuf, const ushort_t* __restrict__ bias,
                 ushort_t* __restrict__ obuf) {
    __shared__ ushort_t Ks[128 * KROW];
    __shared__ ushort_t Ps[64 * PROW];
    __shared__ float linv[64];

    const int t = threadIdx.x;
    const int wave = t >> 6, lane = t & 63;
    const int l16 = lane & 15, quad = lane >> 4;
    const int bid = blockIdx.x;
    const int b = bid & 31;
    const int hq = bid >> 5;
    const int h = hq & 7;
    const int qt = hq >> 3;            // 0..12
    const int bh = b * NH + h;
    const int i0 = qt * 64;
    const int mvalid = min(4, (NN - i0 + 15) >> 4);
    const bool swave = wave < mvalid;
    const float SC2 = 0.25505679f;     // (1/sqrt(32)) * log2(e)

    const ushort_t* qbase = qbuf + ((size_t)bh * NN + i0) * KD;
    const ushort_t* kbase = kbuf + (size_t)bh * NNP * KD;
    const ushort_t* vbase = vbuf + (size_t)bh * VD * NNP;
    const ushort_t* bbase = bias + ((size_t)h * NN + i0) * NNP;

    // Q fragment: A[m=qrow(l16)][k=d(quad*8+j)]
    shortx8 qf = {};
    if (swave) qf = *(const shortx8*)(qbase + (wave * 16 + l16) * KD + quad * 8);

    float lacc[4] = {0.f, 0.f, 0.f, 0.f};
    floatx4 oacc[4][2] = {};

    // K staging via global_load_lds: wave stages rows [w*16, w*16+16) and [64+w*16, ...)
    // LDS dest is wave-uniform base + lane*16B -> row-major 64B rows (KROW=32 ushorts).
    const int srow = lane >> 2, sq4 = lane & 3;
    ushort_t* kl0 = Ks + (size_t)(wave * 16) * KROW;
    ushort_t* kl1 = Ks + (size_t)(64 + wave * 16) * KROW;
    const ushort_t* kg = kbase + (size_t)(wave * 16 + srow) * KD + sq4 * 8;

    // prologue: stage chunk 0
    gld16(kl0, kg);
    gld16(kl1, kg + (size_t)64 * KD);

    for (int c = 0; c < 7; ++c) {
        __syncthreads();   // K(c) visible (barrier drains vmcnt); Ps free from PV(c-1)

        // ---- S phase: wave w -> q-rows [16w, 16w+16); D: col=key(l16), row=qrow(quad*4+r)
        if (swave) {
            #pragma unroll
            for (int jt = 0; jt < 8; ++jt) {
                shortx8 kf = *(const shortx8*)(Ks + (jt * 16 + l16) * KROW + quad * 8);
                floatx4 d = {};
                d = __builtin_amdgcn_mfma_f32_16x16x32_bf16(qf, kf, d, 0, 0, 0);
                const int j = c * 128 + jt * 16 + l16;
                #pragma unroll
                for (int r = 0; r < 4; ++r) {
                    const int lr = wave * 16 + quad * 4 + r;
                    const float bv = bf2f(bbase[(size_t)lr * NNP + j]);
                    const float e = __builtin_amdgcn_exp2f(fmaf(d[r], SC2, bv));
                    lacc[r] += e;
                    Ps[lr * PROW + jt * 16 + l16] = f2bf(e);
                }
            }
        }
        __syncthreads();   // Ps(c) visible; Ks(c) fully consumed

        // ---- async-stage K(c+1) behind PV's MFMA work ----
        if (c < 6) {
            gld16(kl0, kg + (size_t)(c + 1) * 128 * KD);
            gld16(kl1, kg + ((size_t)(c + 1) * 128 + 64) * KD);
        }

        // ---- PV phase: wave -> vd cols [32w, 32w+32) for all m ----
        {
            const ushort_t* vb = vbase + (size_t)(wave * 32) * NNP + c * 128;
            #pragma unroll
            for (int ks = 0; ks < 4; ++ks) {
                shortx8 v0 = *(const shortx8*)(vb + (size_t)l16 * NNP + ks * 32 + quad * 8);
                shortx8 v1 = *(const shortx8*)(vb + (size_t)(16 + l16) * NNP + ks * 32 + quad * 8);
                #pragma unroll
                for (int ms = 0; ms < 4; ++ms) {
                    if (ms < mvalid) {
                        shortx8 af = *(const shortx8*)(Ps + (ms * 16 + l16) * PROW + ks * 32 + quad * 8);
                        oacc[ms][0] = __builtin_amdgcn_mfma_f32_16x16x32_bf16(af, v0, oacc[ms][0], 0, 0, 0);
                        oacc[ms][1] = __builtin_amdgcn_mfma_f32_16x16x32_bf16(af, v1, oacc[ms][1], 0, 0, 0);
                    }
                }
            }
        }
    }

    // ---- row sums: 16-wide butterfly within quads of same rows ----
    if (swave) {
        #pragma unroll
        for (int r = 0; r < 4; ++r) {
            float s = lacc[r];
            s += __shfl_xor(s, 1, 16);
            s += __shfl_xor(s, 2, 16);
            s += __shfl_xor(s, 4, 16);
            s += __shfl_xor(s, 8, 16);
            if (l16 == r) linv[wave * 16 + quad * 4 + r] = 1.0f / s;
        }
    }
    __syncthreads();

    // ---- epilogue: normalize, hardswish, store ----
    #pragma unroll
    for (int ms = 0; ms < 4; ++ms) {
        if (ms < mvalid) {
            #pragma unroll
            for (int vt = 0; vt < 2; ++vt) {
                const int vd = h * VD + wave * 32 + vt * 16 + l16;
                #pragma unroll
                for (int r = 0; r < 4; ++r) {
                    const int row = i0 + ms * 16 + quad * 4 + r;
                    const float o = oacc[ms][vt][r] * linv[ms * 16 + quad * 4 + r];
                    const float hs = o * fminf(fmaxf(o + 3.0f, 0.0f), 6.0f) * (1.0f / 6.0f);
                    obuf[((size_t)b * NN + row) * VAL_ATTN + vd] = f2bf(hs);
                }
            }
        }
    }
}

// ---------------- Proj GEMM (global_load_lds staging) + BN -> fp32 ------
__global__ __launch_bounds__(256, 4)
void proj_gemm(const ushort_t* __restrict__ obuf, const ushort_t* __restrict__ pwb,
               const float* __restrict__ pscale, const float* __restrict__ pshift,
               float* __restrict__ out) {
    __shared__ ushort_t As[128 * 32];
    __shared__ ushort_t Bs[128 * 32];
    const int t = threadIdx.x;
    const int m0 = blockIdx.x * 128;
    const int n0 = blockIdx.y * 128;
    const int wave = t >> 6, lane = t & 63;
    const int wm = wave >> 1, wn = wave & 1;
    const int l16 = lane & 15, quad = lane >> 4;
    const int r4 = lane >> 2, c8 = lane & 3;

    floatx4 acc[4][4] = {};

    const ushort_t* agp = obuf + (size_t)(m0 + wave * 16 + r4) * VAL_ATTN + c8 * 8;
    const ushort_t* bgp = pwb + (size_t)(n0 + wave * 16 + r4) * VAL_ATTN + c8 * 8;
    ushort_t* alp = As + wave * 16 * 32;
    ushort_t* blp = Bs + wave * 16 * 32;

    for (int k0 = 0; k0 < VAL_ATTN; k0 += 32) {
        gld16(alp,           agp + k0);
        gld16(alp + 64 * 32, agp + (size_t)64 * VAL_ATTN + k0);
        gld16(blp,           bgp + k0);
        gld16(blp + 64 * 32, bgp + (size_t)64 * VAL_ATTN + k0);
        __syncthreads();
        shortx8 af[4], bfr[4];
        #pragma unroll
        for (int i = 0; i < 4; ++i)
            af[i] = *(const shortx8*)(As + (wm * 64 + i * 16 + l16) * 32 + quad * 8);
        #pragma unroll
        for (int j = 0; j < 4; ++j)
            bfr[j] = *(const shortx8*)(Bs + (wn * 64 + j * 16 + l16) * 32 + quad * 8);
        #pragma unroll
        for (int i = 0; i < 4; ++i)
            #pragma unroll
            for (int j = 0; j < 4; ++j)
                acc[i][j] = __builtin_amdgcn_mfma_f32_16x16x32_bf16(af[i], bfr[j], acc[i][j], 0, 0, 0);
        __syncthreads();
    }

    #pragma unroll
    for (int j = 0; j < 4; ++j) {
        const int gn = n0 + wn * 64 + j * 16 + l16;
        const float sc = pscale[gn], sh = pshift[gn];
        #pragma unroll
        for (int i = 0; i < 4; ++i) {
            #pragma unroll
            for (int r = 0; r < 4; ++r) {
                const int gm = m0 + wm * 64 + i * 16 + quad * 4 + r;
                out[(size_t)gm * DIMC + gn] = acc[i][j][r] * sc + sh;
            }
        }
    }
}

extern "C" void kernel_launch(void* const* d_in, const int* in_sizes, int n_in,
                              void* d_out, int out_size, void* d_ws, size_t ws_size,
                              hipStream_t stream) {
    const float* x      = (const float*)d_in[0];
    const float* qkv_w  = (const float*)d_in[1];
    const float* qkv_g  = (const float*)d_in[2];
    const float* qkv_b  = (const float*)d_in[3];
    const float* qkv_m  = (const float*)d_in[4];
    const float* qkv_v  = (const float*)d_in[5];
    const float* ab     = (const float*)d_in[6];
    const float* proj_w = (const float*)d_in[7];
    const float* proj_g = (const float*)d_in[8];
    const float* proj_b = (const float*)d_in[9];
    const float* proj_m = (const float*)d_in[10];
    const float* proj_v = (const float*)d_in[11];
    const int*   idxs   = (const int*)d_in[12];
    float* out = (float*)d_out;

    char* ws = (char*)d_ws;
    size_t off = 0;
    auto alloc = [&](size_t bytes) {
        void* p = ws + off;
        off = (off + bytes + 255) & ~(size_t)255;
        return p;
    };
    ushort_t* qbuf = (ushort_t*)alloc((size_t)NB * NH * NN * KD * 2);
    ushort_t* kbuf = (ushort_t*)alloc((size_t)NB * NH * NNP * KD * 2);
    ushort_t* vbuf = (ushort_t*)alloc((size_t)NB * NH * VD * NNP * 2);
    ushort_t* obuf = (ushort_t*)alloc((size_t)NB * NN * VAL_ATTN * 2);
    ushort_t* bias = (ushort_t*)alloc((size_t)NH * NN * NNP * 2);
    ushort_t* xb   = (ushort_t*)alloc((size_t)NB * NN * DIMC * 2);
    ushort_t* wqb  = (ushort_t*)alloc((size_t)QKV_OUT * DIMC * 2);
    ushort_t* pwb  = (ushort_t*)alloc((size_t)DIMC * VAL_ATTN * 2);
    float* qscale = (float*)alloc(QKV_OUT * 4);
    float* qshift = (float*)alloc(QKV_OUT * 4);
    float* pscale = (float*)alloc(DIMC * 4);
    float* pshift = (float*)alloc(DIMC * 4);

    const int nx4 = NB * NN * DIMC / 4;
    const int nw4 = QKV_OUT * DIMC / 4;
    const int np4 = DIMC * VAL_ATTN / 4;
    cvt_bf16<<<(nx4 + 255) / 256, 256, 0, stream>>>(x, xb, nx4);
    cvt_bf16<<<(nw4 + 255) / 256, 256, 0, stream>>>(qkv_w, wqb, nw4);
    cvt_bf16<<<(np4 + 255) / 256, 256, 0, stream>>>(proj_w, pwb, np4);
    bn_prep<<<6, 256, 0, stream>>>(qkv_g, qkv_b, qkv_m, qkv_v, qscale, qshift, QKV_OUT);
    bn_prep<<<2, 256, 0, stream>>>(proj_g, proj_b, proj_m, proj_v, pscale, pshift, DIMC);
    bias_prep<<<(NH * NN * NNP + 255) / 256, 256, 0, stream>>>(ab, idxs, bias);
    qkv_gemm<<<dim3(196, 12), 256, 0, stream>>>(xb, wqb, qscale, qshift, qbuf, kbuf, vbuf);
    attn_kernel<<<dim3(32 * NH * 13), 256, 0, stream>>>(qbuf, kbuf, vbuf, bias, obuf);
    proj_gemm<<<dim3(196, 4), 256, 0, stream>>>(obuf, pwb, pscale, pshift, out);
}